// Round 1
// baseline (10592.669 us; speedup 1.0000x reference)
//
#include <hip/hip_runtime.h>

// Problem constants (reference: B,T,I,H,O = 64,256,512,1024,512)
#define NB 64
#define NT 256
#define NI 512
#define NH 1024
#define NO 512

typedef _Float16 half8 __attribute__((ext_vector_type(8)));
typedef float f32x4 __attribute__((ext_vector_type(4)));

// Workspace layout (bytes):
//   [0, 16777216)            x16   : fp16 copy of x        (64*256*512)
//   [16777216, 50331648)     out1  : fp16 layer-1 outputs  [T][B][H]
//   [50331648, 50593792)     hbuf  : fp16 hidden double-buffer [2][B][H]
//   [50593792, +512)         ctr   : 4 group barrier counters (128B apart)
#define OFF_OUT1 16777216
#define OFF_HBUF 50331648
#define OFF_CTR  50593792

// ---------------- init: fp32->fp16 conversion + zero barrier counters ----------------
__global__ void k_init(const float* __restrict__ x, const float* __restrict__ h0,
                       _Float16* __restrict__ x16, _Float16* __restrict__ hb0,
                       unsigned* __restrict__ ctr)
{
    int i = blockIdx.x * blockDim.x + threadIdx.x;
    if (i < NB * NT * NI) x16[i] = (_Float16)x[i];
    if (i < NB * NH)      hb0[i] = (_Float16)h0[i];
    if (i < 4)            ctr[i * 32] = 0u;
}

// ---------------- persistent two-layer scan ----------------
// Grid: 256 WGs x 256 threads. WG (g,j): batch group g (16 rows), n-slice j (16 cols).
// 4 independent batch groups of 64 WGs each; per-step 64-WG barrier per group.
// Weights live in VGPRs as MFMA B-fragments (loaded once per layer phase).
__launch_bounds__(256, 1)
__global__ void k_scan(const _Float16* __restrict__ x16,
                       _Float16* __restrict__ out1,
                       _Float16* __restrict__ hbuf,
                       const float* __restrict__ Wih1, const float* __restrict__ Whh1,
                       const float* __restrict__ bih1, const float* __restrict__ bhh1,
                       const float* __restrict__ Wih2, const float* __restrict__ Whh2,
                       const float* __restrict__ bih2, const float* __restrict__ bhh2,
                       float* __restrict__ h2out,
                       unsigned* __restrict__ ctr)
{
    __shared__ float zred[3][16][17];   // cross-wave partial sums (waves 1..3)

    const int tid  = threadIdx.x;
    const int wave = tid >> 6;
    const int lane = tid & 63;
    const int quad = lane >> 4;
    const int row  = lane & 15;          // A batch-row / B n-col within the 16x16 tile
    const int g    = blockIdx.x >> 6;    // batch group 0..3
    const int j    = blockIdx.x & 63;    // n-slice 0..63
    const int n0   = j << 4;
    const int brow = (g << 4) + row;     // global batch row this lane loads for A
    const int nglb = n0 + row;           // global output feature this lane holds for B
    unsigned* const my_ctr = ctr + g * 32;

    half8 wreg[16];
    float bias = 0.f;

    // ===================== layer 1: K = 512(x) + 1024(h) = 1536 =====================
    #pragma unroll
    for (int kt = 0; kt < 12; ++kt) {
        const int k0 = wave * 384 + kt * 32 + quad * 8;
        const float* s = (k0 < NI) ? (Wih1 + nglb * NI + k0)
                                   : (Whh1 + nglb * NH + (k0 - NI));
        half8 w;
        #pragma unroll
        for (int e = 0; e < 8; ++e) w[e] = (_Float16)s[e];
        wreg[kt] = w;
    }
    if (wave == 0) bias = bih1[nglb] + bhh1[nglb];

    for (int t = 0; t < NT; ++t) {
        const int r = t;
        const _Float16* const hcur = hbuf + (r & 1) * (NB * NH);
        _Float16* const hnxt = hbuf + ((r & 1) ^ 1) * (NB * NH);

        half8 a[12];
        #pragma unroll
        for (int kt = 0; kt < 12; ++kt) {
            const int k0 = wave * 384 + kt * 32 + quad * 8;
            const _Float16* s = (k0 < NI) ? (x16 + (brow * NT + t) * NI + k0)
                                          : (hcur + brow * NH + (k0 - NI));
            a[kt] = *(const half8*)s;
        }
        f32x4 acc = {0.f, 0.f, 0.f, 0.f};
        #pragma unroll
        for (int kt = 0; kt < 12; ++kt)
            acc = __builtin_amdgcn_mfma_f32_16x16x32_f16(a[kt], wreg[kt], acc, 0, 0, 0);

        if (wave != 0) {
            #pragma unroll
            for (int e = 0; e < 4; ++e) zred[wave - 1][quad * 4 + e][row] = acc[e];
        }
        __syncthreads();
        if (wave == 0) {
            #pragma unroll
            for (int e = 0; e < 4; ++e) {
                const float z = acc[e] + zred[0][quad * 4 + e][row]
                              + zred[1][quad * 4 + e][row] + zred[2][quad * 4 + e][row] + bias;
                const float v = tanhf(z);
                const int b = (g << 4) + (quad << 2) + e;
                const _Float16 hv = (_Float16)v;
                hnxt[b * NH + n0 + row] = hv;
                out1[(t * NB + b) * NH + n0 + row] = hv;
            }
        }
        __syncthreads();
        if (tid == 0) {
            __threadfence();
            __hip_atomic_fetch_add(my_ctr, 1u, __ATOMIC_RELEASE, __HIP_MEMORY_SCOPE_AGENT);
            const unsigned tgt = 64u * (unsigned)(r + 1);
            while (__hip_atomic_load(my_ctr, __ATOMIC_ACQUIRE, __HIP_MEMORY_SCOPE_AGENT) < tgt)
                __builtin_amdgcn_s_sleep(1);
            __threadfence();
        }
        __syncthreads();
    }

    // ===================== layer 2: K = 1024(out1_t) + 1024(h) = 2048 =====================
    // NOTE: reference quirk — layer-2 initial hidden = layer-1 FINAL hidden; parity works
    // out naturally: after r=255 the latest hidden sits in buffer 0, read at r=256.
    #pragma unroll
    for (int kt = 0; kt < 16; ++kt) {
        const int k0 = wave * 512 + kt * 32 + quad * 8;
        const float* s = (k0 < NH) ? (Wih2 + nglb * NH + k0)
                                   : (Whh2 + nglb * NH + (k0 - NH));
        half8 w;
        #pragma unroll
        for (int e = 0; e < 8; ++e) w[e] = (_Float16)s[e];
        wreg[kt] = w;
    }
    if (wave == 0) bias = bih2[nglb] + bhh2[nglb];

    for (int t = 0; t < NT; ++t) {
        const int r = NT + t;
        const _Float16* const hcur = hbuf + (r & 1) * (NB * NH);
        _Float16* const hnxt = hbuf + ((r & 1) ^ 1) * (NB * NH);

        half8 a[16];
        #pragma unroll
        for (int kt = 0; kt < 16; ++kt) {
            const int k0 = wave * 512 + kt * 32 + quad * 8;
            const _Float16* s = (k0 < NH) ? (out1 + (t * NB + brow) * NH + k0)
                                          : (hcur + brow * NH + (k0 - NH));
            a[kt] = *(const half8*)s;
        }
        f32x4 acc = {0.f, 0.f, 0.f, 0.f};
        #pragma unroll
        for (int kt = 0; kt < 16; ++kt)
            acc = __builtin_amdgcn_mfma_f32_16x16x32_f16(a[kt], wreg[kt], acc, 0, 0, 0);

        if (wave != 0) {
            #pragma unroll
            for (int e = 0; e < 4; ++e) zred[wave - 1][quad * 4 + e][row] = acc[e];
        }
        __syncthreads();
        if (wave == 0) {
            #pragma unroll
            for (int e = 0; e < 4; ++e) {
                const float z = acc[e] + zred[0][quad * 4 + e][row]
                              + zred[1][quad * 4 + e][row] + zred[2][quad * 4 + e][row] + bias;
                const float v = tanhf(z);
                const int b = (g << 4) + (quad << 2) + e;
                hnxt[b * NH + n0 + row] = (_Float16)v;
                if (t == NT - 1) h2out[b * NH + n0 + row] = v;   // fp32, straight to d_out
            }
        }
        __syncthreads();
        if (r != 2 * NT - 1) {   // no barrier after the very last step
            if (tid == 0) {
                __threadfence();
                __hip_atomic_fetch_add(my_ctr, 1u, __ATOMIC_RELEASE, __HIP_MEMORY_SCOPE_AGENT);
                const unsigned tgt = 64u * (unsigned)(r + 1);
                while (__hip_atomic_load(my_ctr, __ATOMIC_ACQUIRE, __HIP_MEMORY_SCOPE_AGENT) < tgt)
                    __builtin_amdgcn_s_sleep(1);
                __threadfence();
            }
            __syncthreads();
        }
    }
}

// ---------------- FC + softmax: probs = softmax(h2 @ Wfc^T + bfc) ----------------
__global__ void k_fc(const float* __restrict__ h2, const float* __restrict__ Wfc,
                     const float* __restrict__ bfc, float* __restrict__ probs)
{
    __shared__ float hrow[NH];
    __shared__ float logits[NO];
    __shared__ float red[8];

    const int b = blockIdx.x;
    const int tid = threadIdx.x;
    const int wave = tid >> 6;
    const int lane = tid & 63;

    for (int i = tid; i < NH; i += 256) hrow[i] = h2[b * NH + i];
    __syncthreads();

    float hl[16];
    #pragma unroll
    for (int e = 0; e < 16; ++e) hl[e] = hrow[lane * 16 + e];

    for (int o = wave * 128; o < wave * 128 + 128; ++o) {
        const float* wr = Wfc + o * NH + lane * 16;
        float s = 0.f;
        #pragma unroll
        for (int e = 0; e < 16; ++e) s += hl[e] * wr[e];
        #pragma unroll
        for (int off = 32; off > 0; off >>= 1) s += __shfl_down(s, off, 64);
        if (lane == 0) logits[o] = s + bfc[o];
    }
    __syncthreads();

    float m = -1e30f;
    for (int o = tid; o < NO; o += 256) m = fmaxf(m, logits[o]);
    #pragma unroll
    for (int off = 32; off > 0; off >>= 1) m = fmaxf(m, __shfl_down(m, off, 64));
    if (lane == 0) red[wave] = m;
    __syncthreads();
    const float mx = fmaxf(fmaxf(red[0], red[1]), fmaxf(red[2], red[3]));

    float sum = 0.f;
    for (int o = tid; o < NO; o += 256) sum += expf(logits[o] - mx);
    #pragma unroll
    for (int off = 32; off > 0; off >>= 1) sum += __shfl_down(sum, off, 64);
    if (lane == 0) red[4 + wave] = sum;
    __syncthreads();
    const float inv = 1.f / (red[4] + red[5] + red[6] + red[7]);

    for (int o = tid; o < NO; o += 256) probs[b * NO + o] = expf(logits[o] - mx) * inv;
}

extern "C" void kernel_launch(void* const* d_in, const int* in_sizes, int n_in,
                              void* d_out, int out_size, void* d_ws, size_t ws_size,
                              hipStream_t stream)
{
    const float* x    = (const float*)d_in[0];
    const float* h0   = (const float*)d_in[1];
    const float* Wih1 = (const float*)d_in[2];
    const float* Whh1 = (const float*)d_in[3];
    const float* bih1 = (const float*)d_in[4];
    const float* bhh1 = (const float*)d_in[5];
    const float* Wih2 = (const float*)d_in[6];
    const float* Whh2 = (const float*)d_in[7];
    const float* bih2 = (const float*)d_in[8];
    const float* bhh2 = (const float*)d_in[9];
    const float* Wfc  = (const float*)d_in[10];
    const float* bfc  = (const float*)d_in[11];

    float* outp = (float*)d_out;              // [64*512 probs | 64*1024 h2]
    float* h2out = outp + NB * NO;

    char* ws = (char*)d_ws;
    _Float16* x16  = (_Float16*)(ws);
    _Float16* out1 = (_Float16*)(ws + OFF_OUT1);
    _Float16* hbuf = (_Float16*)(ws + OFF_HBUF);
    unsigned* ctr  = (unsigned*)(ws + OFF_CTR);

    // 1) convert x -> fp16, h0 -> hidden buffer 0, zero barrier counters
    hipLaunchKernelGGL(k_init, dim3((NB * NT * NI + 255) / 256), dim3(256), 0, stream,
                       x, h0, x16, hbuf, ctr);

    // 2) persistent two-layer scan (cooperative: all 256 WGs co-resident)
    void* args[] = { &x16, &out1, &hbuf,
                     &Wih1, &Whh1, &bih1, &bhh1,
                     &Wih2, &Whh2, &bih2, &bhh2,
                     &h2out, &ctr };
    hipLaunchCooperativeKernel(reinterpret_cast<void*>(k_scan),
                               dim3(256), dim3(256), args, 0, stream);

    // 3) FC + softmax
    hipLaunchKernelGGL(k_fc, dim3(NB), dim3(256), 0, stream, h2out, Wfc, bfc, outp);
}

// Round 3
// 7872.371 us; speedup vs baseline: 1.3456x; 1.3456x over previous
//
#include <hip/hip_runtime.h>

// Problem constants (reference: B,T,I,H,O = 64,256,512,1024,512)
#define NB 64
#define NT 256
#define NI 512
#define NH 1024
#define NO 512

typedef _Float16 half8 __attribute__((ext_vector_type(8)));
typedef _Float16 half4 __attribute__((ext_vector_type(4)));
typedef float    f32x4 __attribute__((ext_vector_type(4)));

// Workspace layout (bytes) — total < 40 MB (ws >= 50.6 MB proven in round 1)
//   [0, 32M)       out1 : fp16 layer-1 outputs [T][B][H]
//   [32M, 33M)     w1   : fp16 Wih1 [H][I]
//   [33M, 35M)     w2   : fp16 Wih2 [H][H]
//   [35M, 37M)     wh1  : fp16 Whh1 [H][H]
//   [37M, 39M)     wh2  : fp16 Whh2 [H][H]
//   [39M, +256K)   hbuf : fp16 hidden double-buffer [2][B][H]
//   [.., +512)     slots: 4 groups x 32 dwords barrier slots
#define OFF_W1   (32u * 1024u * 1024u)
#define OFF_W2   (OFF_W1 + 1u * 1024u * 1024u)
#define OFF_WH1  (OFF_W2 + 2u * 1024u * 1024u)
#define OFF_WH2  (OFF_WH1 + 2u * 1024u * 1024u)
#define OFF_HBUF (OFF_WH2 + 2u * 1024u * 1024u)
#define OFF_SLOT (OFF_HBUF + 256u * 1024u)

// branchless tanh: 1 - 2/(e^{2z}+1); exp overflow -> inf -> rcp -> 0 -> +1; underflow -> -1
__device__ __forceinline__ float tanh_fast(float z) {
    const float e = __expf(2.0f * z);
    return 1.0f - 2.0f * __builtin_amdgcn_rcpf(e + 1.0f);
}

// ---------------- init: fp32->fp16 staging + zero barrier slots ----------------
__global__ void k_init(const float* __restrict__ h0,
                       const float* __restrict__ Wih1, const float* __restrict__ Wih2,
                       const float* __restrict__ Whh1, const float* __restrict__ Whh2,
                       _Float16* __restrict__ hb0, _Float16* __restrict__ w1,
                       _Float16* __restrict__ w2, _Float16* __restrict__ wh1,
                       _Float16* __restrict__ wh2, unsigned* __restrict__ slots)
{
    const int i = blockIdx.x * 256 + threadIdx.x;
    if (i < NB * NH) hb0[i] = (_Float16)h0[i];
    if (i < NH * NI) w1[i] = (_Float16)Wih1[i];
    if (i < NH * NH) {
        w2[i]  = (_Float16)Wih2[i];
        wh1[i] = (_Float16)Whh1[i];
        wh2[i] = (_Float16)Whh2[i];
    }
    if (i < 128) slots[i] = 0u;
}

#define MFMA4(A, W, base)                                                                     \
    ac0 = __builtin_amdgcn_mfma_f32_16x16x32_f16((A)[(base)+0], (W)[(base)+0], ac0, 0, 0, 0); \
    ac1 = __builtin_amdgcn_mfma_f32_16x16x32_f16((A)[(base)+1], (W)[(base)+1], ac1, 0, 0, 0); \
    ac2 = __builtin_amdgcn_mfma_f32_16x16x32_f16((A)[(base)+2], (W)[(base)+2], ac2, 0, 0, 0); \
    ac3 = __builtin_amdgcn_mfma_f32_16x16x32_f16((A)[(base)+3], (W)[(base)+3], ac3, 0, 0, 0);

// ---------------- persistent two-layer scan ----------------
// 64 WGs x 256 thr (regular launch; 64 blocks on 256 CUs are trivially co-resident).
// WG (g = bid&3, j = bid>>2): batch group g (16 rows), cols [j*64, j*64+64).
// Each wave owns 16 cols, full K; Whh fragments in VGPRs. Data moves with PLAIN
// cached loads/stores. Cross-WG ordering: per-group 16-slot barrier with
// RELEASE slot store (drains + writes back L2) / ACQUIRE slot polls (buffer_inv)
// — the exact agent-scope semantics that round 1 proved on this chip.
__launch_bounds__(256, 1)
__global__ void k_scan(const float* __restrict__ x,
                       const _Float16* __restrict__ wh1,
                       const _Float16* __restrict__ wh2,
                       const float* __restrict__ bih1, const float* __restrict__ bhh1,
                       const float* __restrict__ bih2, const float* __restrict__ bhh2,
                       const _Float16* __restrict__ w1,
                       const _Float16* __restrict__ w2,
                       _Float16* __restrict__ out1,
                       _Float16* __restrict__ hbuf,
                       float* __restrict__ h2out,
                       unsigned* __restrict__ slots)
{
    __shared__ alignas(16) _Float16 tile[4][16][20];   // wave-private transpose tiles

    const int tid  = threadIdx.x;
    const int wv   = tid >> 6;
    const int lane = tid & 63;
    const int quad = lane >> 4;
    const int row  = lane & 15;
    const int bid  = blockIdx.x;
    const int g    = bid & 3;
    const int j    = bid >> 2;
    const int n0   = j * 64 + wv * 16;
    const int nglb = n0 + row;           // output feature this lane holds in B-frags
    const int brow = g * 16 + row;       // batch row this lane loads in A-frags
    unsigned* const gs = slots + g * 32;

    half8 whh[32];                        // recurrent weights: 128 VGPR, resident

    for (int phase = 0; phase < 2; ++phase) {
        const _Float16* const Wf = phase ? wh2 : wh1;
        #pragma unroll
        for (int c = 0; c < 32; ++c)
            whh[c] = *(const half8*)(Wf + (size_t)nglb * NH + c * 32 + quad * 8);
        const float bias = phase ? (bih2[nglb] + bhh2[nglb])
                                 : (bih1[nglb] + bhh1[nglb]);

        for (int t = 0; t < NT; ++t) {
            const int r = phase * NT + t;
            const _Float16* const hcur = hbuf + (size_t)(r & 1) * (NB * NH);
            _Float16* const hnxt = hbuf + (size_t)((r + 1) & 1) * (NB * NH);

            // recurrent A-frags first (longest-latency loads; rest hides under them)
            half8 ah[32];
            const _Float16* const hb = hcur + (size_t)brow * NH + quad * 8;
            #pragma unroll
            for (int c = 0; c < 32; ++c)
                ah[c] = *(const half8*)(hb + c * 32);

            f32x4 ac0 = {0.f, 0.f, 0.f, 0.f};
            f32x4 ac1 = ac0, ac2 = ac0, ac3 = ac0;

            if (phase == 0) {
                // input part: K=512 of x (fp32, cached) x Wih1 (fp16, cached)
                const float*    const xb = x  + ((size_t)brow * NT + t) * NI + quad * 8;
                const _Float16* const wb = w1 + (size_t)nglb * NI + quad * 8;
                #pragma unroll
                for (int c = 0; c < 16; c += 4) {
                    const f32x4* q0 = (const f32x4*)(xb + (c + 0) * 32);
                    const f32x4* q1 = (const f32x4*)(xb + (c + 1) * 32);
                    const f32x4* q2 = (const f32x4*)(xb + (c + 2) * 32);
                    const f32x4* q3 = (const f32x4*)(xb + (c + 3) * 32);
                    half8 a0, a1, a2, a3;
                    #pragma unroll
                    for (int e = 0; e < 4; ++e) {
                        a0[e] = (_Float16)q0[0][e]; a0[e + 4] = (_Float16)q0[1][e];
                        a1[e] = (_Float16)q1[0][e]; a1[e + 4] = (_Float16)q1[1][e];
                        a2[e] = (_Float16)q2[0][e]; a2[e + 4] = (_Float16)q2[1][e];
                        a3[e] = (_Float16)q3[0][e]; a3[e + 4] = (_Float16)q3[1][e];
                    }
                    half8 b0 = *(const half8*)(wb + (c + 0) * 32);
                    half8 b1 = *(const half8*)(wb + (c + 1) * 32);
                    half8 b2 = *(const half8*)(wb + (c + 2) * 32);
                    half8 b3 = *(const half8*)(wb + (c + 3) * 32);
                    ac0 = __builtin_amdgcn_mfma_f32_16x16x32_f16(a0, b0, ac0, 0, 0, 0);
                    ac1 = __builtin_amdgcn_mfma_f32_16x16x32_f16(a1, b1, ac1, 0, 0, 0);
                    ac2 = __builtin_amdgcn_mfma_f32_16x16x32_f16(a2, b2, ac2, 0, 0, 0);
                    ac3 = __builtin_amdgcn_mfma_f32_16x16x32_f16(a3, b3, ac3, 0, 0, 0);
                }
            } else {
                // input part: K=1024 of out1[t] (fp16, cached) x Wih2 (fp16, cached)
                const _Float16* const ob = out1 + ((size_t)t * NB + brow) * NH + quad * 8;
                const _Float16* const wb = w2 + (size_t)nglb * NH + quad * 8;
                #pragma unroll
                for (int c = 0; c < 32; c += 4) {
                    half8 a0 = *(const half8*)(ob + (c + 0) * 32);
                    half8 a1 = *(const half8*)(ob + (c + 1) * 32);
                    half8 a2 = *(const half8*)(ob + (c + 2) * 32);
                    half8 a3 = *(const half8*)(ob + (c + 3) * 32);
                    half8 b0 = *(const half8*)(wb + (c + 0) * 32);
                    half8 b1 = *(const half8*)(wb + (c + 1) * 32);
                    half8 b2 = *(const half8*)(wb + (c + 2) * 32);
                    half8 b3 = *(const half8*)(wb + (c + 3) * 32);
                    ac0 = __builtin_amdgcn_mfma_f32_16x16x32_f16(a0, b0, ac0, 0, 0, 0);
                    ac1 = __builtin_amdgcn_mfma_f32_16x16x32_f16(a1, b1, ac1, 0, 0, 0);
                    ac2 = __builtin_amdgcn_mfma_f32_16x16x32_f16(a2, b2, ac2, 0, 0, 0);
                    ac3 = __builtin_amdgcn_mfma_f32_16x16x32_f16(a3, b3, ac3, 0, 0, 0);
                }
            }

            // recurrent part: K=1024 of h x Whh (registers)
            MFMA4(ah, whh, 0)  MFMA4(ah, whh, 4)  MFMA4(ah, whh, 8)  MFMA4(ah, whh, 12)
            MFMA4(ah, whh, 16) MFMA4(ah, whh, 20) MFMA4(ah, whh, 24) MFMA4(ah, whh, 28)

            // epilogue: z -> tanh -> wave-internal LDS transpose -> 8B plain stores
            f32x4 z;
            #pragma unroll
            for (int e = 0; e < 4; ++e)
                z[e] = ac0[e] + ac1[e] + ac2[e] + ac3[e] + bias;

            // C/D layout: this lane holds (b = g*16 + quad*4+e, n = nglb)
            half4 tv;
            #pragma unroll
            for (int e = 0; e < 4; ++e)
                tv[e] = (_Float16)tanh_fast(z[e]);
            *(half4*)&tile[wv][row][quad * 4] = tv;    // [n_local][b_local]

            // wave-lockstep transpose read: lane now holds b_local = row, 4 contig n
            half4 pk;
            pk[0] = tile[wv][quad * 4 + 0][row];
            pk[1] = tile[wv][quad * 4 + 1][row];
            pk[2] = tile[wv][quad * 4 + 2][row];
            pk[3] = tile[wv][quad * 4 + 3][row];
            const int bg = g * 16 + row;
            const int nc = n0 + quad * 4;

            if (r != 2 * NT - 1) {
                *(half4*)(hnxt + (size_t)bg * NH + nc) = pk;
            } else {
                f32x4 fo;
                fo[0] = (float)pk[0]; fo[1] = (float)pk[1];
                fo[2] = (float)pk[2]; fo[3] = (float)pk[3];
                *(f32x4*)(h2out + (size_t)bg * NH + nc) = fo;   // final h2, fp32
            }
            if (phase == 0)
                *(half4*)(out1 + ((size_t)t * NB + bg) * NH + nc) = pk;

            // ---- per-group barrier: RELEASE slot store + ACQUIRE slot polls ----
            if (r != 2 * NT - 1) {
                __syncthreads();   // compiler drains each wave's stores (vmcnt 0) first
                if (tid == 0)
                    __hip_atomic_store(gs + j, (unsigned)(r + 1),
                                       __ATOMIC_RELEASE, __HIP_MEMORY_SCOPE_AGENT);
                const unsigned tgt = (unsigned)(r + 1);
                while (true) {
                    const unsigned v = __hip_atomic_load(gs + (lane & 15),
                                                         __ATOMIC_ACQUIRE,
                                                         __HIP_MEMORY_SCOPE_AGENT);
                    if (__all((int)(v >= tgt))) break;
                }
            }
        }
    }
}

// ---------------- FC + softmax: probs = softmax(h2 @ Wfc^T + bfc) ----------------
__global__ void k_fc(const float* __restrict__ h2, const float* __restrict__ Wfc,
                     const float* __restrict__ bfc, float* __restrict__ probs)
{
    __shared__ float hrow[NH];
    __shared__ float logits[NO];
    __shared__ float red[8];

    const int b = blockIdx.x;
    const int tid = threadIdx.x;
    const int wave = tid >> 6;
    const int lane = tid & 63;

    for (int i = tid; i < NH; i += 256) hrow[i] = h2[b * NH + i];
    __syncthreads();

    float hl[16];
    #pragma unroll
    for (int e = 0; e < 16; ++e) hl[e] = hrow[lane * 16 + e];

    for (int o = wave * 128; o < wave * 128 + 128; ++o) {
        const float* wr = Wfc + o * NH + lane * 16;
        float s = 0.f;
        #pragma unroll
        for (int e = 0; e < 16; ++e) s += hl[e] * wr[e];
        #pragma unroll
        for (int off = 32; off > 0; off >>= 1) s += __shfl_down(s, off, 64);
        if (lane == 0) logits[o] = s + bfc[o];
    }
    __syncthreads();

    float m = -1e30f;
    for (int o = tid; o < NO; o += 256) m = fmaxf(m, logits[o]);
    #pragma unroll
    for (int off = 32; off > 0; off >>= 1) m = fmaxf(m, __shfl_down(m, off, 64));
    if (lane == 0) red[wave] = m;
    __syncthreads();
    const float mx = fmaxf(fmaxf(red[0], red[1]), fmaxf(red[2], red[3]));

    float sum = 0.f;
    for (int o = tid; o < NO; o += 256) sum += expf(logits[o] - mx);
    #pragma unroll
    for (int off = 32; off > 0; off >>= 1) sum += __shfl_down(sum, off, 64);
    if (lane == 0) red[4 + wave] = sum;
    __syncthreads();
    const float inv = 1.f / (red[4] + red[5] + red[6] + red[7]);

    for (int o = tid; o < NO; o += 256) probs[b * NO + o] = expf(logits[o] - mx) * inv;
}

extern "C" void kernel_launch(void* const* d_in, const int* in_sizes, int n_in,
                              void* d_out, int out_size, void* d_ws, size_t ws_size,
                              hipStream_t stream)
{
    const float* x    = (const float*)d_in[0];
    const float* h0   = (const float*)d_in[1];
    const float* Wih1 = (const float*)d_in[2];
    const float* Whh1 = (const float*)d_in[3];
    const float* bih1 = (const float*)d_in[4];
    const float* bhh1 = (const float*)d_in[5];
    const float* Wih2 = (const float*)d_in[6];
    const float* Whh2 = (const float*)d_in[7];
    const float* bih2 = (const float*)d_in[8];
    const float* bhh2 = (const float*)d_in[9];
    const float* Wfc  = (const float*)d_in[10];
    const float* bfc  = (const float*)d_in[11];

    float* outp  = (float*)d_out;             // [64*512 probs | 64*1024 h2]
    float* h2out = outp + NB * NO;

    char* ws = (char*)d_ws;
    _Float16* out1 = (_Float16*)ws;
    _Float16* w1   = (_Float16*)(ws + OFF_W1);
    _Float16* w2   = (_Float16*)(ws + OFF_W2);
    _Float16* wh1  = (_Float16*)(ws + OFF_WH1);
    _Float16* wh2  = (_Float16*)(ws + OFF_WH2);
    _Float16* hbuf = (_Float16*)(ws + OFF_HBUF);
    unsigned* slots= (unsigned*)(ws + OFF_SLOT);

    // 1) stage fp16 weights + h0, zero barrier slots
    hipLaunchKernelGGL(k_init, dim3(4096), dim3(256), 0, stream,
                       h0, Wih1, Wih2, Whh1, Whh2, hbuf, w1, w2, wh1, wh2, slots);

    // 2) persistent two-layer scan — regular launch, 64 WGs (trivially co-resident)
    hipLaunchKernelGGL(k_scan, dim3(64), dim3(256), 0, stream,
                       x, wh1, wh2, bih1, bhh1, bih2, bhh2,
                       w1, w2, out1, hbuf, h2out, slots);

    // 3) FC + softmax
    hipLaunchKernelGGL(k_fc, dim3(NB), dim3(256), 0, stream, h2out, Wfc, bfc, outp);
}

// Round 4
// 7338.202 us; speedup vs baseline: 1.4435x; 1.0728x over previous
//
#include <hip/hip_runtime.h>

// Problem constants (reference: B,T,I,H,O = 64,256,512,1024,512)
#define NB 64
#define NT 256
#define NI 512
#define NH 1024
#define NO 512

typedef _Float16 half8 __attribute__((ext_vector_type(8)));
typedef _Float16 half4 __attribute__((ext_vector_type(4)));
typedef float    f32x4 __attribute__((ext_vector_type(4)));

union H8 { half8 v; unsigned long long u[2]; };
union H4 { half4 v; unsigned long long u; };

// Workspace layout (bytes) — total < 40 MB
//   [0, 32M)       out1 : fp16 layer-1 outputs [T][B][H]
//   [32M, 33M)     w1   : fp16 Wih1 [H][I]
//   [33M, 35M)     w2   : fp16 Wih2 [H][H]
//   [35M, 37M)     wh1  : fp16 Whh1 [H][H]
//   [37M, 39M)     wh2  : fp16 Whh2 [H][H]
//   [39M, +256K)   hbuf : fp16 hidden double-buffer [2][B][H]
//   [.., +512)     slots: 4 groups x 32 dwords barrier slots
#define OFF_W1   (32u * 1024u * 1024u)
#define OFF_W2   (OFF_W1 + 1u * 1024u * 1024u)
#define OFF_WH1  (OFF_W2 + 2u * 1024u * 1024u)
#define OFF_WH2  (OFF_WH1 + 2u * 1024u * 1024u)
#define OFF_HBUF (OFF_WH2 + 2u * 1024u * 1024u)
#define OFF_SLOT (OFF_HBUF + 256u * 1024u)

// ---- relaxed agent-scope ops: compile to sc-flagged ld/st, NO buffer_inv / wbl2 ----
__device__ __forceinline__ unsigned ald32(const unsigned* p) {
    return __hip_atomic_load(p, __ATOMIC_RELAXED, __HIP_MEMORY_SCOPE_AGENT);
}
__device__ __forceinline__ void ast32(unsigned* p, unsigned v) {
    __hip_atomic_store(p, v, __ATOMIC_RELAXED, __HIP_MEMORY_SCOPE_AGENT);
}
__device__ __forceinline__ unsigned long long ald64(const void* p) {
    return __hip_atomic_load((const unsigned long long*)p,
                             __ATOMIC_RELAXED, __HIP_MEMORY_SCOPE_AGENT);
}
__device__ __forceinline__ void ast64(void* p, unsigned long long v) {
    __hip_atomic_store((unsigned long long*)p, v,
                       __ATOMIC_RELAXED, __HIP_MEMORY_SCOPE_AGENT);
}
__device__ __forceinline__ half8 load_h8(const _Float16* p) {
    H8 r;
    r.u[0] = ald64(p);
    r.u[1] = ald64(p + 4);
    return r.v;
}

// branchless tanh: 1 - 2/(e^{2z}+1); exp overflow -> inf -> rcp -> 0 -> +1; underflow -> -1
__device__ __forceinline__ float tanh_fast(float z) {
    const float e = __expf(2.0f * z);
    return 1.0f - 2.0f * __builtin_amdgcn_rcpf(e + 1.0f);
}

// ---------------- init: fp32->fp16 staging + zero barrier slots ----------------
__global__ void k_init(const float* __restrict__ h0,
                       const float* __restrict__ Wih1, const float* __restrict__ Wih2,
                       const float* __restrict__ Whh1, const float* __restrict__ Whh2,
                       _Float16* __restrict__ hb0, _Float16* __restrict__ w1,
                       _Float16* __restrict__ w2, _Float16* __restrict__ wh1,
                       _Float16* __restrict__ wh2, unsigned* __restrict__ slots)
{
    const int i = blockIdx.x * 256 + threadIdx.x;
    if (i < NB * NH) hb0[i] = (_Float16)h0[i];
    if (i < NH * NI) w1[i] = (_Float16)Wih1[i];
    if (i < NH * NH) {
        w2[i]  = (_Float16)Wih2[i];
        wh1[i] = (_Float16)Whh1[i];
        wh2[i] = (_Float16)Whh2[i];
    }
    if (i < 128) slots[i] = 0u;
}

#define MFMA4(A, W, base)                                                                     \
    ac0 = __builtin_amdgcn_mfma_f32_16x16x32_f16((A)[(base)+0], (W)[(base)+0], ac0, 0, 0, 0); \
    ac1 = __builtin_amdgcn_mfma_f32_16x16x32_f16((A)[(base)+1], (W)[(base)+1], ac1, 0, 0, 0); \
    ac2 = __builtin_amdgcn_mfma_f32_16x16x32_f16((A)[(base)+2], (W)[(base)+2], ac2, 0, 0, 0); \
    ac3 = __builtin_amdgcn_mfma_f32_16x16x32_f16((A)[(base)+3], (W)[(base)+3], ac3, 0, 0, 0);

// wait until all 16 group slots >= tgt (wave 0 polls, others park at barrier)
#define POLL_WAIT(tgt)                                                                        \
    {                                                                                         \
        if (wv == 0) {                                                                        \
            while (true) {                                                                    \
                const unsigned v_ = ald32(gs + (lane & 15));                                  \
                if (__all((int)(v_ >= (unsigned)(tgt)))) break;                               \
            }                                                                                 \
        }                                                                                     \
        __syncthreads();                                                                      \
    }

// recurrent part: load h frags (sc-flagged, LLC) + 32 MFMA on register Whh
#define RECURRENT(hbase)                                                                      \
    {                                                                                         \
        const _Float16* const hb_ = (hbase) + (size_t)brow * NH + quad * 8;                   \
        half8 ahh[32];                                                                        \
        _Pragma("unroll")                                                                     \
        for (int c = 0; c < 32; ++c) ahh[c] = load_h8(hb_ + c * 32);                          \
        MFMA4(ahh, whh, 0)  MFMA4(ahh, whh, 4)  MFMA4(ahh, whh, 8)  MFMA4(ahh, whh, 12)      \
        MFMA4(ahh, whh, 16) MFMA4(ahh, whh, 20) MFMA4(ahh, whh, 24) MFMA4(ahh, whh, 28)      \
    }

// input part, phase 0: acc = x[t] (fp32, cached) x Wih1 (fp16, cached)
#define PRE_P0(t_)                                                                            \
    {                                                                                         \
        const float*    const xb_ = x  + ((size_t)brow * NT + (t_)) * NI + quad * 8;          \
        const _Float16* const wb_ = w1 + (size_t)nglb * NI + quad * 8;                        \
        ac0 = (f32x4){0.f, 0.f, 0.f, 0.f}; ac1 = ac0; ac2 = ac0; ac3 = ac0;                   \
        _Pragma("unroll")                                                                     \
        for (int c = 0; c < 16; c += 4) {                                                     \
            const f32x4* q0 = (const f32x4*)(xb_ + (c + 0) * 32);                             \
            const f32x4* q1 = (const f32x4*)(xb_ + (c + 1) * 32);                             \
            const f32x4* q2 = (const f32x4*)(xb_ + (c + 2) * 32);                             \
            const f32x4* q3 = (const f32x4*)(xb_ + (c + 3) * 32);                             \
            half8 a0, a1, a2, a3;                                                             \
            _Pragma("unroll")                                                                 \
            for (int e = 0; e < 4; ++e) {                                                     \
                a0[e] = (_Float16)q0[0][e]; a0[e + 4] = (_Float16)q0[1][e];                   \
                a1[e] = (_Float16)q1[0][e]; a1[e + 4] = (_Float16)q1[1][e];                   \
                a2[e] = (_Float16)q2[0][e]; a2[e + 4] = (_Float16)q2[1][e];                   \
                a3[e] = (_Float16)q3[0][e]; a3[e + 4] = (_Float16)q3[1][e];                   \
            }                                                                                 \
            half8 b0 = *(const half8*)(wb_ + (c + 0) * 32);                                   \
            half8 b1 = *(const half8*)(wb_ + (c + 1) * 32);                                   \
            half8 b2 = *(const half8*)(wb_ + (c + 2) * 32);                                   \
            half8 b3 = *(const half8*)(wb_ + (c + 3) * 32);                                   \
            ac0 = __builtin_amdgcn_mfma_f32_16x16x32_f16(a0, b0, ac0, 0, 0, 0);               \
            ac1 = __builtin_amdgcn_mfma_f32_16x16x32_f16(a1, b1, ac1, 0, 0, 0);               \
            ac2 = __builtin_amdgcn_mfma_f32_16x16x32_f16(a2, b2, ac2, 0, 0, 0);               \
            ac3 = __builtin_amdgcn_mfma_f32_16x16x32_f16(a3, b3, ac3, 0, 0, 0);               \
        }                                                                                     \
    }

// input part, phase 1: acc = out1[t] (fp16, cached; first-touch-after-write) x Wih2
#define PRE_P1(t_)                                                                            \
    {                                                                                         \
        const _Float16* const ob_ = out1 + ((size_t)(t_) * NB + brow) * NH + quad * 8;        \
        const _Float16* const wb_ = w2 + (size_t)nglb * NH + quad * 8;                        \
        ac0 = (f32x4){0.f, 0.f, 0.f, 0.f}; ac1 = ac0; ac2 = ac0; ac3 = ac0;                   \
        _Pragma("unroll")                                                                     \
        for (int c = 0; c < 32; c += 4) {                                                     \
            half8 a0 = *(const half8*)(ob_ + (c + 0) * 32);                                   \
            half8 a1 = *(const half8*)(ob_ + (c + 1) * 32);                                   \
            half8 a2 = *(const half8*)(ob_ + (c + 2) * 32);                                   \
            half8 a3 = *(const half8*)(ob_ + (c + 3) * 32);                                   \
            half8 b0 = *(const half8*)(wb_ + (c + 0) * 32);                                   \
            half8 b1 = *(const half8*)(wb_ + (c + 1) * 32);                                   \
            half8 b2 = *(const half8*)(wb_ + (c + 2) * 32);                                   \
            half8 b3 = *(const half8*)(wb_ + (c + 3) * 32);                                   \
            ac0 = __builtin_amdgcn_mfma_f32_16x16x32_f16(a0, b0, ac0, 0, 0, 0);               \
            ac1 = __builtin_amdgcn_mfma_f32_16x16x32_f16(a1, b1, ac1, 0, 0, 0);               \
            ac2 = __builtin_amdgcn_mfma_f32_16x16x32_f16(a2, b2, ac2, 0, 0, 0);               \
            ac3 = __builtin_amdgcn_mfma_f32_16x16x32_f16(a3, b3, ac3, 0, 0, 0);               \
        }                                                                                     \
    }

// ---------------- persistent two-layer scan ----------------
// 64 WGs x 256 thr (regular launch; trivially co-resident on 256 CUs).
// WG (g = bid&3, j = bid>>2): batch group g (16 rows), cols [j*64, j*64+64).
// Each wave owns 16 cols, full K; Whh fp16 fragments resident in VGPRs.
// Cross-WG data (h, out1 stores, slots) moves via RELAXED agent-scope (sc-flagged)
// ops -> LLC, leaving L1/L2 warm (no buffer_inv / wbl2 per step). Ordering:
// __syncthreads' vmcnt(0) drain before the slot signal; consumer polls relaxed.
// Software pipeline: step t+1's h-independent input GEMM runs between signal and poll.
__launch_bounds__(256, 1)
__global__ void k_scan(const float* __restrict__ x,
                       const _Float16* __restrict__ wh1,
                       const _Float16* __restrict__ wh2,
                       const float* __restrict__ bih1, const float* __restrict__ bhh1,
                       const float* __restrict__ bih2, const float* __restrict__ bhh2,
                       const _Float16* __restrict__ w1,
                       const _Float16* __restrict__ w2,
                       _Float16* __restrict__ out1,
                       _Float16* __restrict__ hbuf,
                       float* __restrict__ h2out,
                       unsigned* __restrict__ slots)
{
    __shared__ alignas(16) _Float16 tile[4][16][20];   // wave-private transpose tiles

    const int tid  = threadIdx.x;
    const int wv   = tid >> 6;
    const int lane = tid & 63;
    const int quad = lane >> 4;
    const int row  = lane & 15;
    const int bid  = blockIdx.x;
    const int g    = bid & 3;
    const int j    = bid >> 2;
    const int n0   = j * 64 + wv * 16;
    const int nglb = n0 + row;           // output feature this lane holds in B-frags
    const int brow = g * 16 + row;       // batch row this lane loads in A-frags
    unsigned* const gs = slots + g * 32;

    half8 whh[32];                        // recurrent weights: 128 VGPR, resident
    f32x4 ac0, ac1, ac2, ac3;

    // =========================== phase 0: h' = tanh(x Wih1^T + h Whh1^T + b) ===========
    #pragma unroll
    for (int c = 0; c < 32; ++c)
        whh[c] = *(const half8*)(wh1 + (size_t)nglb * NH + c * 32 + quad * 8);
    float bias = bih1[nglb] + bhh1[nglb];

    PRE_P0(0)
    for (int t = 0; t < NT; ++t) {
        const int r = t;
        if (r > 0) POLL_WAIT(r)                      // h[r] visible in LLC

        RECURRENT(hbuf + (size_t)(r & 1) * (NB * NH))

        // epilogue: z -> tanh -> wave-internal LDS transpose -> 8B LLC stores
        f32x4 z;
        #pragma unroll
        for (int e = 0; e < 4; ++e) z[e] = ac0[e] + ac1[e] + ac2[e] + ac3[e] + bias;
        half4 tv;
        #pragma unroll
        for (int e = 0; e < 4; ++e) tv[e] = (_Float16)tanh_fast(z[e]);
        *(half4*)&tile[wv][row][quad * 4] = tv;      // [n_local][b_local]
        H4 pk;                                        // wave-lockstep transpose read
        pk.v[0] = tile[wv][quad * 4 + 0][row];
        pk.v[1] = tile[wv][quad * 4 + 1][row];
        pk.v[2] = tile[wv][quad * 4 + 2][row];
        pk.v[3] = tile[wv][quad * 4 + 3][row];
        const int bg = g * 16 + row;
        const int nc = n0 + quad * 4;
        ast64(hbuf + (size_t)((r + 1) & 1) * (NB * NH) + (size_t)bg * NH + nc, pk.u);
        ast64(out1 + ((size_t)t * NB + bg) * NH + nc, pk.u);

        __syncthreads();                             // drains vmcnt(0) per wave first
        if (tid == 0) ast32(gs + j, (unsigned)(r + 1));
        if (t + 1 < NT) PRE_P0(t + 1)                // overlap with other WGs' catch-up
    }

    // =========================== phase 1: h' = tanh(out1 Wih2^T + h Whh2^T + b) ========
    // reference quirk: layer-2 initial hidden = layer-1 FINAL hidden (parity lines up:
    // step r=255 stored h[256] into hbuf[0], read at r=256).
    #pragma unroll
    for (int c = 0; c < 32; ++c)
        whh[c] = *(const half8*)(wh2 + (size_t)nglb * NH + c * 32 + quad * 8);
    bias = bih2[nglb] + bhh2[nglb];

    PRE_P1(0)
    for (int t = 0; t < NT; ++t) {
        const int r = NT + t;
        POLL_WAIT(r)

        RECURRENT(hbuf + (size_t)(r & 1) * (NB * NH))

        f32x4 z;
        #pragma unroll
        for (int e = 0; e < 4; ++e) z[e] = ac0[e] + ac1[e] + ac2[e] + ac3[e] + bias;
        half4 tv;
        #pragma unroll
        for (int e = 0; e < 4; ++e) tv[e] = (_Float16)tanh_fast(z[e]);
        *(half4*)&tile[wv][row][quad * 4] = tv;
        H4 pk;
        pk.v[0] = tile[wv][quad * 4 + 0][row];
        pk.v[1] = tile[wv][quad * 4 + 1][row];
        pk.v[2] = tile[wv][quad * 4 + 2][row];
        pk.v[3] = tile[wv][quad * 4 + 3][row];
        const int bg = g * 16 + row;
        const int nc = n0 + quad * 4;
        if (r != 2 * NT - 1) {
            ast64(hbuf + (size_t)((r + 1) & 1) * (NB * NH) + (size_t)bg * NH + nc, pk.u);
        } else {
            f32x4 fo;                                 // final h2, fp32, plain store
            fo[0] = (float)pk.v[0]; fo[1] = (float)pk.v[1];
            fo[2] = (float)pk.v[2]; fo[3] = (float)pk.v[3];
            *(f32x4*)(h2out + (size_t)bg * NH + nc) = fo;
        }

        __syncthreads();
        if (tid == 0) ast32(gs + j, (unsigned)(r + 1));
        if (t + 1 < NT) PRE_P1(t + 1)
    }
}

// ---------------- FC + softmax: probs = softmax(h2 @ Wfc^T + bfc) ----------------
__global__ void k_fc(const float* __restrict__ h2, const float* __restrict__ Wfc,
                     const float* __restrict__ bfc, float* __restrict__ probs)
{
    __shared__ float hrow[NH];
    __shared__ float logits[NO];
    __shared__ float red[8];

    const int b = blockIdx.x;
    const int tid = threadIdx.x;
    const int wave = tid >> 6;
    const int lane = tid & 63;

    for (int i = tid; i < NH; i += 256) hrow[i] = h2[b * NH + i];
    __syncthreads();

    float hl[16];
    #pragma unroll
    for (int e = 0; e < 16; ++e) hl[e] = hrow[lane * 16 + e];

    for (int o = wave * 128; o < wave * 128 + 128; ++o) {
        const float* wr = Wfc + o * NH + lane * 16;
        float s = 0.f;
        #pragma unroll
        for (int e = 0; e < 16; ++e) s += hl[e] * wr[e];
        #pragma unroll
        for (int off = 32; off > 0; off >>= 1) s += __shfl_down(s, off, 64);
        if (lane == 0) logits[o] = s + bfc[o];
    }
    __syncthreads();

    float m = -1e30f;
    for (int o = tid; o < NO; o += 256) m = fmaxf(m, logits[o]);
    #pragma unroll
    for (int off = 32; off > 0; off >>= 1) m = fmaxf(m, __shfl_down(m, off, 64));
    if (lane == 0) red[wave] = m;
    __syncthreads();
    const float mx = fmaxf(fmaxf(red[0], red[1]), fmaxf(red[2], red[3]));

    float sum = 0.f;
    for (int o = tid; o < NO; o += 256) sum += expf(logits[o] - mx);
    #pragma unroll
    for (int off = 32; off > 0; off >>= 1) sum += __shfl_down(sum, off, 64);
    if (lane == 0) red[4 + wave] = sum;
    __syncthreads();
    const float inv = 1.f / (red[4] + red[5] + red[6] + red[7]);

    for (int o = tid; o < NO; o += 256) probs[b * NO + o] = expf(logits[o] - mx) * inv;
}

extern "C" void kernel_launch(void* const* d_in, const int* in_sizes, int n_in,
                              void* d_out, int out_size, void* d_ws, size_t ws_size,
                              hipStream_t stream)
{
    const float* x    = (const float*)d_in[0];
    const float* h0   = (const float*)d_in[1];
    const float* Wih1 = (const float*)d_in[2];
    const float* Whh1 = (const float*)d_in[3];
    const float* bih1 = (const float*)d_in[4];
    const float* bhh1 = (const float*)d_in[5];
    const float* Wih2 = (const float*)d_in[6];
    const float* Whh2 = (const float*)d_in[7];
    const float* bih2 = (const float*)d_in[8];
    const float* bhh2 = (const float*)d_in[9];
    const float* Wfc  = (const float*)d_in[10];
    const float* bfc  = (const float*)d_in[11];

    float* outp  = (float*)d_out;             // [64*512 probs | 64*1024 h2]
    float* h2out = outp + NB * NO;

    char* ws = (char*)d_ws;
    _Float16* out1 = (_Float16*)ws;
    _Float16* w1   = (_Float16*)(ws + OFF_W1);
    _Float16* w2   = (_Float16*)(ws + OFF_W2);
    _Float16* wh1  = (_Float16*)(ws + OFF_WH1);
    _Float16* wh2  = (_Float16*)(ws + OFF_WH2);
    _Float16* hbuf = (_Float16*)(ws + OFF_HBUF);
    unsigned* slots= (unsigned*)(ws + OFF_SLOT);

    // 1) stage fp16 weights + h0, zero barrier slots
    hipLaunchKernelGGL(k_init, dim3(4096), dim3(256), 0, stream,
                       h0, Wih1, Wih2, Whh1, Whh2, hbuf, w1, w2, wh1, wh2, slots);

    // 2) persistent two-layer scan — regular launch, 64 WGs (trivially co-resident)
    hipLaunchKernelGGL(k_scan, dim3(64), dim3(256), 0, stream,
                       x, wh1, wh2, bih1, bhh1, bih2, bhh2,
                       w1, w2, out1, hbuf, h2out, slots);

    // 3) FC + softmax
    hipLaunchKernelGGL(k_fc, dim3(NB), dim3(256), 0, stream, h2out, Wfc, bfc, outp);
}